// Round 18
// baseline (2988.463 us; speedup 1.0000x reference)
//
#include <hip/hip_runtime.h>
#include <math.h>

#define NN 512      // nodes
#define NB 256      // batch
#define NT 200      // time steps
#define TPB 256

typedef unsigned long long u64;
typedef _Float16 half8 __attribute__((ext_vector_type(8)));
typedef float f32x4 __attribute__((ext_vector_type(4)));

// ws layout (float offsets)
#define WS_WM  0                        // Wm fp32 [NN*NN]; k_ode: tagged buf parity 1
#define WS_WC  (NN*NN)                  // Wc fp16 [NN*NN halves]
#define WS_C   (WS_WC + NN*NN/2)        // c = b2*Wm^T fp32 [NN]
#define WS_X0  (WS_C + NN)              // x0 fp32 [NB*NN]
#define WS_HB0 (WS_X0 + NB*NN)          // tagged buf parity 0: 256 rows x 256 u64

// ---- MALL-coherent ops via compiler-generated scoped atomics (no asm) ----
__device__ __forceinline__ void sysst_u64(u64* p, u64 v) {
  __hip_atomic_store(p, v, __ATOMIC_RELAXED, __HIP_MEMORY_SCOPE_SYSTEM);
}
__device__ __forceinline__ u64 sysld_u64(const u64* p) {
  return __hip_atomic_load(p, __ATOMIC_RELAXED, __HIP_MEMORY_SCOPE_SYSTEM);
}
__device__ __forceinline__ void sysst_f1(float* p, float v) {
  __hip_atomic_store(p, v, __ATOMIC_RELAXED, __HIP_MEMORY_SCOPE_SYSTEM);
}
__device__ __forceinline__ float sysld_f1(const float* p) {
  return __hip_atomic_load(p, __ATOMIC_RELAXED, __HIP_MEMORY_SCOPE_SYSTEM);
}
// pack two h values + epoch tag into one atomic u64
__device__ __forceinline__ u64 packh(float a, float b, unsigned tag) {
  union { _Float16 h[2]; unsigned u; } lo;
  lo.h[0] = (_Float16)a; lo.h[1] = (_Float16)b;
  return ((u64)tag << 32) | (u64)lo.u;
}

__global__ __launch_bounds__(256)
void k_init(const float* __restrict__ W1, const float* __restrict__ mask,
            const float* __restrict__ x_init, float* __restrict__ ws,
            float* __restrict__ out) {
  int gt = blockIdx.x * 256 + threadIdx.x;
  int stride = gridDim.x * 256;
  for (int i = gt; i < NN * NN; i += stride) ws[WS_WM + i] = W1[i] * mask[i];
  for (int i = gt; i < NB * NN / 2; i += stride) {
    u64 q = ((const u64*)x_init)[i];
    int r = i >> 8, np = i & 255;
    *((u64*)(out + (size_t)r * NT * NN) + np) = q;   // traj[:,0,:]
  }
}

// One block per node j: Wc[j][:] (fp16), c[j], and x0[:,j] = y0 . Wm[j,:].
__global__ __launch_bounds__(128)
void k_prep(const float* __restrict__ W2g, const float* __restrict__ b2,
            const float* __restrict__ x_init, float* __restrict__ ws) {
  __shared__ float w1row[NN];
  const int j = blockIdx.x;
  const int t = threadIdx.x;
  const float* wm = ws + WS_WM + (size_t)j * NN;
  for (int i = t; i < NN; i += 128) w1row[i] = wm[i];
  __syncthreads();

  f32x4 acc = {0.f, 0.f, 0.f, 0.f};
  for (int m = 0; m < NN; ++m) {
    float w = w1row[m];
    if (w != 0.f)
      acc += w * ((const f32x4*)(W2g + (size_t)m * NN))[t];
  }
  _Float16* wcrow = (_Float16*)(ws + WS_WC) + (size_t)j * NN;
#pragma unroll
  for (int e = 0; e < 4; ++e) wcrow[4 * t + e] = (_Float16)acc[e];

  if (t == 0) {
    float s = 0.f;
    for (int m = 0; m < NN; ++m)
      if (w1row[m] != 0.f) s += b2[m] * w1row[m];
    ws[WS_C + j] = s;
  }

#pragma unroll
  for (int rr = 0; rr < 2; ++rr) {
    int r = t + rr * 128;
    const float* y0 = x_init + (size_t)r * NN;
    float s = 0.f;
    for (int m = 0; m < NN; ++m) {
      float w = w1row[m];
      if (w != 0.f) s = fmaf(y0[m], w, s);
    }
    sysst_f1(ws + WS_X0 + (size_t)r * NN + j, s);
  }
}

// Unpack 4 tagged u64 (8 cols) into the LDS plane (swizzle key = row).
__device__ __forceinline__ void unpack_write(_Float16* __restrict__ plane,
                                             u64 v0, u64 v1, u64 v2, u64 v3,
                                             int tid) {
  const int row = tid >> 6, g = tid & 63;
  union { unsigned u[4]; half8 h; } x;
  x.u[0] = (unsigned)v0; x.u[1] = (unsigned)v1;
  x.u[2] = (unsigned)v2; x.u[3] = (unsigned)v3;
  ((half8*)plane)[row * 64 + (g ^ row)] = x.h;
}

// Full-K single-pass GEMM, dual accumulators. A-plane key = rc&3;
// B-plane key = rc&7 (weights written with key col&7). Separate keys (r16).
__device__ __forceinline__ void gemm8(const _Float16* plane, const _Float16* wb,
                                      int rc, int kg, int wv, float res[4]) {
  const int swzA = rc & 3;
  const int swzB = rc & 7;
  const half8* pA = (const half8*)plane;
  const half8* pB = (const half8*)wb;
  const int abase = (rc & 3) * 64;
  const int bbase = (wv * 16 + rc) * 64;
  f32x4 ae = {0.f, 0.f, 0.f, 0.f};
  f32x4 ao = {0.f, 0.f, 0.f, 0.f};
#pragma unroll
  for (int kt = 0; kt < 16; kt += 2) {
    const int k0 = kt * 4 + kg;
    const int k1 = (kt + 1) * 4 + kg;
    ae = __builtin_amdgcn_mfma_f32_16x16x32_f16(pA[abase + (k0 ^ swzA)],
                                                pB[bbase + (k0 ^ swzB)],
                                                ae, 0, 0, 0);
    ao = __builtin_amdgcn_mfma_f32_16x16x32_f16(pA[abase + (k1 ^ swzA)],
                                                pB[bbase + (k1 ^ swzB)],
                                                ao, 0, 0, 0);
  }
#pragma unroll
  for (int r = 0; r < 4; ++r) res[r] = ae[r] + ao[r];
}

__global__ __launch_bounds__(TPB, 1)
void k_ode(const float* __restrict__ tspan,
           const float* __restrict__ W2g,
           const float* __restrict__ b1,
           const float* __restrict__ b2,
           float* __restrict__ ws,
           float* __restrict__ out,
           const float* __restrict__ x_init) {
  extern __shared__ _Float16 ldsh[];
  _Float16* wc = ldsh;                 // [64 cols][64 granules] 64KB
  _Float16* w2 = ldsh + 32768;         // 64KB
  // 4 h-planes at ldsh+65536: chain {0,1} x parity {0,1}, 2048 halves each.
  // Addresses computed arithmetically at use site (no LDS pointer arrays —
  // aggregate init of addrspace(3) pointers fails to compile on gfx950).

  const int bid = blockIdx.x;          // 0..255
  const int cg = bid & 7, rgA = bid >> 3;   // rgA 0..31
  const int r0p[2] = {rgA * 4, rgA * 4 + 128};
  const int j0 = cg * 64;
  const int tid = threadIdx.x;
  const int lane = tid & 63, wv = tid >> 6;
  const int rc = lane & 15, kg = lane >> 4;
  const int mycol = j0 + wv * 16 + rc;
  const bool act = (kg == 0);          // lane owns rows r0p[p]+0..3 (col mycol)

  // tagged exchange buffers: [256 rows][256 u64], parity ping-pong
  u64* hbt0 = (u64*)(ws + WS_HB0);
  u64* hbt1 = (u64*)(ws + WS_WM);

  // --- prologue: Wc (fp16 in ws) and W2 (fp32 global) -> LDS planes ---
  {
    const int col = tid >> 2;          // 0..63
    const int part = tid & 3;          // 0..3, 16 granules each
    const half8* s1 = (const half8*)((const _Float16*)(ws + WS_WC)
                                     + (size_t)(j0 + col) * NN) + part * 16;
    const float* s2 = W2g + (size_t)(j0 + col) * NN + part * 128;
    half8* d1 = (half8*)wc;
    half8* d2 = (half8*)w2;
    const int key = col & 7;
#pragma unroll
    for (int i = 0; i < 16; ++i) {
      int g = part * 16 + i;
      int idx = col * 64 + (g ^ key);
      d1[idx] = s1[i];
      half8 hv;
#pragma unroll
      for (int e = 0; e < 8; ++e) hv[e] = (_Float16)s2[i * 8 + e];
      d2[idx] = hv;
    }
  }
  const float b1s = b1[mycol], b2s = b2[mycol];
  const float c_own = ws[WS_C + mycol];

  // latch both chains' state; store h1(t=0) tagged 0 into parity-0 buffer
  float xb[2][4], yb[2][4], H[2][4];
  if (act) {
#pragma unroll
    for (int p = 0; p < 2; ++p)
#pragma unroll
      for (int r = 0; r < 4; ++r) {
        int row = r0p[p] + r;
        xb[p][r] = sysld_f1(ws + WS_X0 + (size_t)row * NN + mycol);
        yb[p][r] = x_init[(size_t)row * NN + mycol];
        float h = tanhf(xb[p][r] + b1s);
        H[p][r] = h;
        float hn = __shfl_down(h, 1);
        if ((rc & 1) == 0)
          sysst_u64(hbt0 + (size_t)row * 256 + (mycol >> 1), packh(h, hn, 0u));
      }
  }
  __syncthreads();

  float res[4], res2[4];
  const int row_g = tid >> 6;          // this thread's staged row (0..3)
  const int gidx = (tid & 63) * 4;     // first u64 of its 8-col granule

  for (int t = 0; t < NT - 1; ++t) {
    const float dt = tspan[t + 1] - tspan[t];
    const float c6 = dt / 6.0f;
#pragma unroll 1
    for (int s = 0; s < 4; ++s) {
      const int q = t * 4 + s;
      const unsigned wtag = (unsigned)(q + 1);
      u64* rb = (q & 1) ? hbt1 : hbt0;
      u64* wr = (q & 1) ? hbt0 : hbt1;
      const u64* rdA = rb + (size_t)(r0p[0] + row_g) * 256 + gidx;
      const u64* rdB = rb + (size_t)(r0p[1] + row_g) * 256 + gidx;
      _Float16* plA = ldsh + 65536 + (q & 1) * 2048;          // chain 0
      _Float16* plB = ldsh + 65536 + 4096 + (q & 1) * 2048;   // chain 1

      // --- chain A: tag-checked stage (loads ARE the poll) ---
      u64 a0, a1, a2, a3;
      for (;;) {
        a0 = sysld_u64(rdA);     a1 = sysld_u64(rdA + 1);
        a2 = sysld_u64(rdA + 2); a3 = sysld_u64(rdA + 3);
        bool ok = ((unsigned)(a0 >> 32) == (unsigned)q) &
                  ((unsigned)(a1 >> 32) == (unsigned)q) &
                  ((unsigned)(a2 >> 32) == (unsigned)q) &
                  ((unsigned)(a3 >> 32) == (unsigned)q);
        if (__all(ok)) break;
        __builtin_amdgcn_s_sleep(1);
      }
      // speculative B loads fly under A's gemm
      u64 b0 = sysld_u64(rdB),       b1v_ = sysld_u64(rdB + 1);
      u64 b2v_ = sysld_u64(rdB + 2), b3 = sysld_u64(rdB + 3);

      unpack_write(plA, a0, a1, a2, a3, tid);
      __syncthreads();
      gemm8(plA, wc, rc, kg, wv, res);
      if (s == 3) gemm8(plA, w2, rc, kg, wv, res2);
      if (act) {
        if (s < 3) {
          const float a = (s == 2) ? dt : dt * 0.5f;
#pragma unroll
          for (int r = 0; r < 4; ++r) {
            float xs = xb[0][r] + a * (res[r] + c_own);
            float h = tanhf(xs + b1s);
            float st;
            if (s == 2) { H[0][r] += h;       st = H[0][r]; }
            else        { H[0][r] += 2.f * h; st = h;       }
            float sn = __shfl_down(st, 1);
            if ((rc & 1) == 0)
              sysst_u64(wr + (size_t)(r0p[0] + r) * 256 + (mycol >> 1),
                        packh(st, sn, wtag));
          }
        } else {
#pragma unroll
          for (int r = 0; r < 4; ++r) {
            int row = r0p[0] + r;
            xb[0][r] += c6 * res[r] + dt * c_own;
            yb[0][r] += c6 * res2[r] + dt * b2s;
            out[((size_t)row * NT + (t + 1)) * NN + mycol] = yb[0][r];
            float h = tanhf(xb[0][r] + b1s);
            H[0][r] = h;
            float hn = __shfl_down(h, 1);
            if ((rc & 1) == 0)
              sysst_u64(wr + (size_t)row * 256 + (mycol >> 1),
                        packh(h, hn, wtag));
          }
        }
      }

      // --- chain B: verify speculative loads, retry if early ---
      for (;;) {
        bool ok = ((unsigned)(b0 >> 32) == (unsigned)q) &
                  ((unsigned)(b1v_ >> 32) == (unsigned)q) &
                  ((unsigned)(b2v_ >> 32) == (unsigned)q) &
                  ((unsigned)(b3 >> 32) == (unsigned)q);
        if (__all(ok)) break;
        __builtin_amdgcn_s_sleep(1);
        b0 = sysld_u64(rdB);       b1v_ = sysld_u64(rdB + 1);
        b2v_ = sysld_u64(rdB + 2); b3 = sysld_u64(rdB + 3);
      }
      unpack_write(plB, b0, b1v_, b2v_, b3, tid);
      __syncthreads();
      gemm8(plB, wc, rc, kg, wv, res);
      if (s == 3) gemm8(plB, w2, rc, kg, wv, res2);
      if (act) {
        if (s < 3) {
          const float a = (s == 2) ? dt : dt * 0.5f;
#pragma unroll
          for (int r = 0; r < 4; ++r) {
            float xs = xb[1][r] + a * (res[r] + c_own);
            float h = tanhf(xs + b1s);
            float st;
            if (s == 2) { H[1][r] += h;       st = H[1][r]; }
            else        { H[1][r] += 2.f * h; st = h;       }
            float sn = __shfl_down(st, 1);
            if ((rc & 1) == 0)
              sysst_u64(wr + (size_t)(r0p[1] + r) * 256 + (mycol >> 1),
                        packh(st, sn, wtag));
          }
        } else {
#pragma unroll
          for (int r = 0; r < 4; ++r) {
            int row = r0p[1] + r;
            xb[1][r] += c6 * res[r] + dt * c_own;
            yb[1][r] += c6 * res2[r] + dt * b2s;
            out[((size_t)row * NT + (t + 1)) * NN + mycol] = yb[1][r];
            float h = tanhf(xb[1][r] + b1s);
            H[1][r] = h;
            float hn = __shfl_down(h, 1);
            if ((rc & 1) == 0)
              sysst_u64(wr + (size_t)row * 256 + (mycol >> 1),
                        packh(h, hn, wtag));
          }
        }
      }
    }
  }
}

extern "C" void kernel_launch(void* const* d_in, const int* in_sizes, int n_in,
                              void* d_out, int out_size, void* d_ws, size_t ws_size,
                              hipStream_t stream) {
  const float* x_init = (const float*)d_in[0];
  const float* tspan  = (const float*)d_in[1];
  const float* W1     = (const float*)d_in[2];
  const float* b1     = (const float*)d_in[3];
  const float* W2     = (const float*)d_in[4];
  const float* b2     = (const float*)d_in[5];
  const float* mask   = (const float*)d_in[6];
  float* out = (float*)d_out;
  float* ws  = (float*)d_ws;

  hipLaunchKernelGGL(k_init, dim3(256), dim3(256), 0, stream,
                     W1, mask, x_init, ws, out);
  hipLaunchKernelGGL(k_prep, dim3(512), dim3(128), 0, stream,
                     W2, b2, x_init, ws);

  const unsigned ldsBytes = 144 * 1024;  // wc 64K + w2 64K + 4 planes x 4K
  (void)hipFuncSetAttribute((const void*)k_ode,
                            hipFuncAttributeMaxDynamicSharedMemorySize,
                            (int)ldsBytes);

  // 256 blocks x 144KB = 1 block/CU; two independent 4-row chains per block.
  // Tag-in-data exchange: each u64 = {2 fp16 h, 32b slot tag}, atomically
  // stored at MALL — the stage loads themselves are the synchronization.
  // No flags, no release fences; 1 __syncthreads per chain slot.
  hipLaunchKernelGGL(k_ode, dim3(256), dim3(TPB), ldsBytes, stream,
                     tspan, W2, b1, b2, ws, out, x_init);
}

// Round 19
// 2707.684 us; speedup vs baseline: 1.1037x; 1.1037x over previous
//
#include <hip/hip_runtime.h>
#include <math.h>

#define NN 512      // nodes
#define NB 256      // batch
#define NT 200      // time steps
#define TPB 256
#define NTEAM 8     // blocks per team (64 cols each)

typedef unsigned long long u64;
typedef _Float16 half8 __attribute__((ext_vector_type(8)));
typedef float f32x4 __attribute__((ext_vector_type(4)));

// ws layout (float offsets)
#define WS_WM  0                        // Wm fp32 [NN*NN]; later hb16[1] overlay
#define WS_WC  (NN*NN)                  // Wc fp16 [NN*NN halves]
#define WS_C   (WS_WC + NN*NN/2)        // c = b2*Wm^T fp32 [NN]
#define WS_X0  (WS_C + NN)              // x0 fp32 [NB*NN]
#define WS_HB0 (WS_X0 + NB*NN)          // hb16[0] fp16 [NB*NN halves]
#define WS_CNT (WS_HB0 + NB*NN/2)       // flags: 64 teams x 8 blk x 16 u32

// ---- MALL-coherent ops via compiler-generated scoped atomics (no asm) ----
__device__ __forceinline__ void sysst_u64(u64* p, u64 v) {
  __hip_atomic_store(p, v, __ATOMIC_RELAXED, __HIP_MEMORY_SCOPE_SYSTEM);
}
__device__ __forceinline__ u64 sysld_u64(const u64* p) {
  return __hip_atomic_load(p, __ATOMIC_RELAXED, __HIP_MEMORY_SCOPE_SYSTEM);
}
__device__ __forceinline__ void sysst_f1(float* p, float v) {
  __hip_atomic_store(p, v, __ATOMIC_RELAXED, __HIP_MEMORY_SCOPE_SYSTEM);
}
__device__ __forceinline__ float sysld_f1(const float* p) {
  return __hip_atomic_load(p, __ATOMIC_RELAXED, __HIP_MEMORY_SCOPE_SYSTEM);
}
__device__ __forceinline__ void sysst_u16(unsigned short* p, unsigned short v) {
  __hip_atomic_store(p, v, __ATOMIC_RELAXED, __HIP_MEMORY_SCOPE_SYSTEM);
}
__device__ __forceinline__ void sysst_h(_Float16* p, float v) {
  union { _Float16 hf; unsigned short us; } cv; cv.hf = (_Float16)v;
  sysst_u16((unsigned short*)p, cv.us);
}

// Light barriers: execution/LDS ordering WITHOUT the vmcnt(0) drain that
// __syncthreads() imposes (which serializes in-flight MALL loads/stores).
__device__ __forceinline__ void barrier_exec() {      // convergence only
  asm volatile("" ::: "memory");
  __builtin_amdgcn_s_barrier();
  __builtin_amdgcn_sched_barrier(0);
}
__device__ __forceinline__ void barrier_lds() {       // ds_write -> ds_read
  asm volatile("s_waitcnt lgkmcnt(0)" ::: "memory");
  __builtin_amdgcn_s_barrier();
  __builtin_amdgcn_sched_barrier(0);
}

__global__ __launch_bounds__(256)
void k_init(const float* __restrict__ W1, const float* __restrict__ mask,
            const float* __restrict__ x_init, float* __restrict__ ws,
            float* __restrict__ out) {
  int gt = blockIdx.x * 256 + threadIdx.x;
  int stride = gridDim.x * 256;
  for (int i = gt; i < NN * NN; i += stride) ws[WS_WM + i] = W1[i] * mask[i];
  for (int i = gt; i < NB * NN / 2; i += stride) {
    u64 q = ((const u64*)x_init)[i];
    int r = i >> 8, np = i & 255;
    *((u64*)(out + (size_t)r * NT * NN) + np) = q;   // traj[:,0,:]
  }
  if (gt < 64 * NTEAM * 16)
    __hip_atomic_store(((unsigned*)(ws + WS_CNT)) + gt, 0u,
                       __ATOMIC_RELAXED, __HIP_MEMORY_SCOPE_SYSTEM);
}

// One block per node j: Wc[j][:] (fp16), c[j], and x0[:,j] = y0 . Wm[j,:].
__global__ __launch_bounds__(128)
void k_prep(const float* __restrict__ W2g, const float* __restrict__ b2,
            const float* __restrict__ x_init, float* __restrict__ ws) {
  __shared__ float w1row[NN];
  const int j = blockIdx.x;
  const int t = threadIdx.x;
  const float* wm = ws + WS_WM + (size_t)j * NN;
  for (int i = t; i < NN; i += 128) w1row[i] = wm[i];
  __syncthreads();

  f32x4 acc = {0.f, 0.f, 0.f, 0.f};
  for (int m = 0; m < NN; ++m) {
    float w = w1row[m];
    if (w != 0.f)
      acc += w * ((const f32x4*)(W2g + (size_t)m * NN))[t];
  }
  _Float16* wcrow = (_Float16*)(ws + WS_WC) + (size_t)j * NN;
#pragma unroll
  for (int e = 0; e < 4; ++e) wcrow[4 * t + e] = (_Float16)acc[e];

  if (t == 0) {
    float s = 0.f;
    for (int m = 0; m < NN; ++m)
      if (w1row[m] != 0.f) s += b2[m] * w1row[m];
    ws[WS_C + j] = s;
  }

#pragma unroll
  for (int rr = 0; rr < 2; ++rr) {
    int r = t + rr * 128;
    const float* y0 = x_init + (size_t)r * NN;
    float s = 0.f;
    for (int m = 0; m < NN; ++m) {
      float w = w1row[m];
      if (w != 0.f) s = fmaf(y0[m], w, s);
    }
    sysst_f1(ws + WS_X0 + (size_t)r * NN + j, s);
  }
}

// wait: poll 8 per-block flags, then EXEC barrier only (no vmcnt drain —
// MALL-direct data is causally ordered: teammates stored data, full-sync
// drained it, then stored the flag; flag-at-MALL implies data-at-MALL).
__device__ __forceinline__ void team_wait(unsigned* flagsp, unsigned target) {
  if (threadIdx.x < NTEAM) {
    while (__hip_atomic_load(flagsp + threadIdx.x * 16, __ATOMIC_RELAXED,
                             __HIP_MEMORY_SCOPE_AGENT) < target)
      __builtin_amdgcn_s_sleep(1);
  }
  barrier_exec();
}
// release: FULL sync (drains each wave's vmcnt -> h stores at MALL), then flag
__device__ __forceinline__ void team_release(unsigned* flagsp, int cg, unsigned e) {
  __syncthreads();
  if (threadIdx.x == 0)
    __hip_atomic_store(flagsp + cg * 16, e, __ATOMIC_RELAXED,
                       __HIP_MEMORY_SCOPE_SYSTEM);
}

// Async-STAGE split for a 4-row chain: issue 2 u64 sys loads early, write the
// half8 granule into the LDS plane late. plane = [4 rows][64 granules] = 4KB.
struct St { u64 a0, a1; };
__device__ __forceinline__ St stage_load(const _Float16* __restrict__ src,
                                         int tid) {
  const int row = tid >> 6;        // 0..3 (one row per wave)
  const int g = tid & 63;          // granule
  const u64* s = (const u64*)(src + (size_t)row * NN) + g * 2;
  St v; v.a0 = sysld_u64(s); v.a1 = sysld_u64(s + 1);
  return v;
}
__device__ __forceinline__ void stage_write(_Float16* __restrict__ plane,
                                            const St& v, int tid) {
  const int row = tid >> 6;
  const int g = tid & 63;
  union { u64 q[2]; half8 h; } u; u.q[0] = v.a0; u.q[1] = v.a1;
  ((half8*)plane)[row * 64 + (g ^ row)] = u.h;
}

// Full-K single-pass GEMM, dual accumulators. A-plane key = rc&3 (4 rows,
// lanes rc>=4 duplicate row rc&3); B-plane key = rc&7 (weights written with
// key col&7). Separate keys (r16-proven).
__device__ __forceinline__ void gemm8(const _Float16* plane, const _Float16* wb,
                                      int rc, int kg, int wv, float res[4]) {
  const int swzA = rc & 3;
  const int swzB = rc & 7;
  const half8* pA = (const half8*)plane;
  const half8* pB = (const half8*)wb;
  const int abase = (rc & 3) * 64;
  const int bbase = (wv * 16 + rc) * 64;
  f32x4 ae = {0.f, 0.f, 0.f, 0.f};
  f32x4 ao = {0.f, 0.f, 0.f, 0.f};
#pragma unroll
  for (int kt = 0; kt < 16; kt += 2) {
    const int k0 = kt * 4 + kg;
    const int k1 = (kt + 1) * 4 + kg;
    ae = __builtin_amdgcn_mfma_f32_16x16x32_f16(pA[abase + (k0 ^ swzA)],
                                                pB[bbase + (k0 ^ swzB)],
                                                ae, 0, 0, 0);
    ao = __builtin_amdgcn_mfma_f32_16x16x32_f16(pA[abase + (k1 ^ swzA)],
                                                pB[bbase + (k1 ^ swzB)],
                                                ao, 0, 0, 0);
  }
#pragma unroll
  for (int r = 0; r < 4; ++r) res[r] = ae[r] + ao[r];
}

__global__ __launch_bounds__(TPB, 1)
void k_ode(const float* __restrict__ tspan,
           const float* __restrict__ W2g,
           const float* __restrict__ b1,
           const float* __restrict__ b2,
           float* __restrict__ ws,
           float* __restrict__ out,
           const float* __restrict__ x_init) {
  extern __shared__ _Float16 ldsh[];
  _Float16* wc  = ldsh;                // [64 cols][64 granules] 64KB
  _Float16* w2  = ldsh + 32768;        // 64KB
  _Float16* plA = ldsh + 65536;        // [4 rows][64 granules] 4KB
  _Float16* plB = ldsh + 67584;        // 4KB  -> 136KB total

  const int bid = blockIdx.x;          // 0..255
  const int cg = bid & 7, rgA = bid >> 3;   // rgA 0..31; chain B team rgA+32
  const int r0p[2] = {rgA * 4, rgA * 4 + 128};
  const int j0 = cg * 64;
  const int tid = threadIdx.x;
  const int lane = tid & 63, wv = tid >> 6;
  const int rc = lane & 15, kg = lane >> 4;
  const int mycol = j0 + wv * 16 + rc;
  const bool act = (kg == 0);          // lane owns rows r0p[p]+0..3 (col mycol)

  unsigned* flbase = (unsigned*)(ws + WS_CNT);
  unsigned* flp0 = flbase + rgA * (NTEAM * 16);
  unsigned* flp1 = flbase + (rgA + 32) * (NTEAM * 16);
  // slot-parity ping-pong: slot q reads hb[q&1], writes hb[(q+1)&1]
  _Float16* hb0 = (_Float16*)(ws + WS_HB0);
  _Float16* hb1 = (_Float16*)(ws + WS_WM);

  // --- prologue: Wc (fp16 in ws) and W2 (fp32 global) -> LDS planes ---
  {
    const int col = tid >> 2;          // 0..63
    const int part = tid & 3;          // 0..3, 16 granules each
    const half8* s1 = (const half8*)((const _Float16*)(ws + WS_WC)
                                     + (size_t)(j0 + col) * NN) + part * 16;
    const float* s2 = W2g + (size_t)(j0 + col) * NN + part * 128;
    half8* d1 = (half8*)wc;
    half8* d2 = (half8*)w2;
    const int key = col & 7;
#pragma unroll
    for (int i = 0; i < 16; ++i) {
      int g = part * 16 + i;
      int idx = col * 64 + (g ^ key);
      d1[idx] = s1[i];
      half8 hv;
#pragma unroll
      for (int e = 0; e < 8; ++e) hv[e] = (_Float16)s2[i * 8 + e];
      d2[idx] = hv;
    }
  }
  const float b1s = b1[mycol], b2s = b2[mycol];
  const float c_own = ws[WS_C + mycol];

  // latch both chains' state; store h1(t=0) fp16 into hb0; flags = 1
  float xb[2][4], yb[2][4], H[2][4];
  if (act) {
#pragma unroll
    for (int p = 0; p < 2; ++p)
#pragma unroll
      for (int r = 0; r < 4; ++r) {
        int row = r0p[p] + r;
        xb[p][r] = sysld_f1(ws + WS_X0 + (size_t)row * NN + mycol);
        yb[p][r] = x_init[(size_t)row * NN + mycol];
        float h = tanhf(xb[p][r] + b1s);
        H[p][r] = h;
        sysst_h(hb0 + (size_t)row * NN + mycol, h);
      }
  }
  __syncthreads();   // full: drain vmcnt -> h1 MALL-visible
  if (tid == 0) {
    __hip_atomic_store(flp0 + cg * 16, 1u, __ATOMIC_RELAXED,
                       __HIP_MEMORY_SCOPE_SYSTEM);
    __hip_atomic_store(flp1 + cg * 16, 1u, __ATOMIC_RELAXED,
                       __HIP_MEMORY_SCOPE_SYSTEM);
  }

  float res[4], res2[4];

  for (int t = 0; t < NT - 1; ++t) {
    const float dt = tspan[t + 1] - tspan[t];
    const float c6 = dt / 6.0f;
#pragma unroll 1
    for (int s = 0; s < 4; ++s) {
      const int q = t * 4 + s;
      const unsigned target = (unsigned)(q + 1);
      const _Float16* rdb = (q & 1) ? hb1 : hb0;
      _Float16* wrb = (q & 1) ? hb0 : hb1;

      // --- issue phase: wait A, launch A loads; wait B, launch B loads.
      // team_wait no longer drains vmcnt, so A loads genuinely fly under
      // B's poll, and B loads fly under A's stage-write + gemm.
      team_wait(flp0, target);
      St va = stage_load(rdb + (size_t)r0p[0] * NN, tid);
      team_wait(flp1, target);
      St vb = stage_load(rdb + (size_t)r0p[1] * NN, tid);

      // --- chain A slot ---
      stage_write(plA, va, tid);       // waits va only (vmcnt counted)
      barrier_lds();                   // LDS ordering; vb stays in flight
      gemm8(plA, wc, rc, kg, wv, res);
      if (s == 3) gemm8(plA, w2, rc, kg, wv, res2);
      if (act) {
        if (s < 3) {
          const float a = (s == 2) ? dt : dt * 0.5f;
#pragma unroll
          for (int r = 0; r < 4; ++r) {
            float xs = xb[0][r] + a * (res[r] + c_own);
            float h = tanhf(xs + b1s);
            float st;
            if (s == 2) { H[0][r] += h;       st = H[0][r]; }
            else        { H[0][r] += 2.f * h; st = h;       }
            sysst_h(wrb + (size_t)(r0p[0] + r) * NN + mycol, st);
          }
        } else {
#pragma unroll
          for (int r = 0; r < 4; ++r) {
            int row = r0p[0] + r;
            xb[0][r] += c6 * res[r] + dt * c_own;
            yb[0][r] += c6 * res2[r] + dt * b2s;
            out[((size_t)row * NT + (t + 1)) * NN + mycol] = yb[0][r];
            float h = tanhf(xb[0][r] + b1s);
            H[0][r] = h;
            sysst_h(wrb + (size_t)row * NN + mycol, h);
          }
        }
      }
      team_release(flp0, cg, target + 1);   // full sync (drains A stores)

      // --- chain B slot ---
      stage_write(plB, vb, tid);       // vb already drained by release sync
      barrier_lds();
      gemm8(plB, wc, rc, kg, wv, res);
      if (s == 3) gemm8(plB, w2, rc, kg, wv, res2);
      if (act) {
        if (s < 3) {
          const float a = (s == 2) ? dt : dt * 0.5f;
#pragma unroll
          for (int r = 0; r < 4; ++r) {
            float xs = xb[1][r] + a * (res[r] + c_own);
            float h = tanhf(xs + b1s);
            float st;
            if (s == 2) { H[1][r] += h;       st = H[1][r]; }
            else        { H[1][r] += 2.f * h; st = h;       }
            sysst_h(wrb + (size_t)(r0p[1] + r) * NN + mycol, st);
          }
        } else {
#pragma unroll
          for (int r = 0; r < 4; ++r) {
            int row = r0p[1] + r;
            xb[1][r] += c6 * res[r] + dt * c_own;
            yb[1][r] += c6 * res2[r] + dt * b2s;
            out[((size_t)row * NT + (t + 1)) * NN + mycol] = yb[1][r];
            float h = tanhf(xb[1][r] + b1s);
            H[1][r] = h;
            sysst_h(wrb + (size_t)row * NN + mycol, h);
          }
        }
      }
      team_release(flp1, cg, target + 1);   // full sync (drains B stores)
    }
  }
}

extern "C" void kernel_launch(void* const* d_in, const int* in_sizes, int n_in,
                              void* d_out, int out_size, void* d_ws, size_t ws_size,
                              hipStream_t stream) {
  const float* x_init = (const float*)d_in[0];
  const float* tspan  = (const float*)d_in[1];
  const float* W1     = (const float*)d_in[2];
  const float* b1     = (const float*)d_in[3];
  const float* W2     = (const float*)d_in[4];
  const float* b2     = (const float*)d_in[5];
  const float* mask   = (const float*)d_in[6];
  float* out = (float*)d_out;
  float* ws  = (float*)d_ws;

  hipLaunchKernelGGL(k_init, dim3(256), dim3(256), 0, stream,
                     W1, mask, x_init, ws, out);
  hipLaunchKernelGGL(k_prep, dim3(512), dim3(128), 0, stream,
                     W2, b2, x_init, ws);

  const unsigned ldsBytes = 136 * 1024;  // wc 64K + w2 64K + plA 4K + plB 4K
  (void)hipFuncSetAttribute((const void*)k_ode,
                            hipFuncAttributeMaxDynamicSharedMemorySize,
                            (int)ldsBytes);

  // 256 blocks x 136KB = 1 block/CU; two independent 4-row chains per block.
  // r16 protocol + light barriers: only the two team_release syncs drain
  // vmcnt (flag-publication ordering); wait/stage syncs are exec/LDS-only so
  // cross-chain MALL loads genuinely overlap compute.
  hipLaunchKernelGGL(k_ode, dim3(256), dim3(TPB), ldsBytes, stream,
                     tspan, W2, b1, b2, ws, out, x_init);
}